// Round 1
// baseline (7474.522 us; speedup 1.0000x reference)
//
#include <hip/hip_runtime.h>
#include <math.h>

namespace {

constexpr int B_ = 256, H_ = 64, L0_ = 640, L1_ = 320, L2_ = 160;
constexpr int N2_ = 32, NL_ = 8, NM_ = 3;

// ---------------------------------------------------------------------------
// K precompute: K[m,i,h,l] = 2*Re( sum_n Cc[n] * exp(dtA[n]*l) )
// grid = NM*NL*H blocks, 256 threads
// ---------------------------------------------------------------------------
__global__ void k_compute_K(const float* __restrict__ log_dt,
                            const float* __restrict__ C,
                            const float* __restrict__ logA,
                            const float* __restrict__ Aim,
                            float* __restrict__ Kb) {
  const int bid = blockIdx.x;
  const int m = bid / (NL_ * H_);
  const int rest = bid % (NL_ * H_);
  const int li = rest / H_;
  const int h = rest % H_;
  const int ph = (m * NL_ + li) * H_ + h;
  __shared__ float sAr[N2_], sAi[N2_], sCr[N2_], sCi[N2_];
  const int tid = threadIdx.x;
  if (tid < N2_) {
    const int n = tid;
    const float dt = expf(log_dt[ph]);
    const float Are = -expf(logA[(size_t)ph * N2_ + n]);
    const float Ai = Aim[(size_t)ph * N2_ + n];
    const float ar = dt * Are, ai = dt * Ai;
    const float er = expf(ar);
    float sn, cs;
    sincosf(ai, &sn, &cs);
    const float mr = er * cs - 1.f;   // exp(dtA)-1, real
    const float mi = er * sn;         // imag
    const float den = Are * Are + Ai * Ai;
    const float qr = (mr * Are + mi * Ai) / den;   // (exp(dtA)-1)/A
    const float qi = (mi * Are - mr * Ai) / den;
    const float C0 = C[((size_t)ph * N2_ + n) * 2 + 0];
    const float C1 = C[((size_t)ph * N2_ + n) * 2 + 1];
    sCr[n] = C0 * qr - C1 * qi;
    sCi[n] = C0 * qi + C1 * qr;
    sAr[n] = ar;
    sAi[n] = ai;
  }
  __syncthreads();
  const int Lm = (m == 0) ? L2_ : (m == 1) ? L1_ : L0_;
  const size_t moff = (m == 0) ? 0
                    : (m == 1) ? (size_t)NL_ * H_ * L2_
                               : (size_t)NL_ * H_ * (L2_ + L1_);
  const size_t off = moff + (size_t)(li * H_ + h) * Lm;
  for (int l = tid; l < Lm; l += blockDim.x) {
    const float fl = (float)l;
    float acc = 0.f;
#pragma unroll
    for (int n = 0; n < N2_; ++n) {
      const float er = expf(sAr[n] * fl);
      float sn, cs;
      sincosf(sAi[n] * fl, &sn, &cs);
      acc += er * (sCr[n] * cs - sCi[n] * sn);
    }
    Kb[off + l] = 2.f * acc;
  }
}

// ---------------------------------------------------------------------------
// Strided conv k=3 s=2 p=1: (B,64,640) -> (B,64,320)
// ---------------------------------------------------------------------------
__global__ void k_conv_d1(const float* __restrict__ x, const float* __restrict__ W,
                          const float* __restrict__ bias, float* __restrict__ out) {
  const int p = blockIdx.x * 256 + threadIdx.x;
  const int t = p % L1_;
  const int o = (p / L1_) % H_;
  const int b = p / (L1_ * H_);
  float acc = bias[o];
  const float* xb = x + (size_t)b * H_ * L0_;
  const float* wo = W + (size_t)o * H_ * 3;
  const int x0 = 2 * t - 1;
  for (int i = 0; i < H_; ++i) {
    const float* xr = xb + (size_t)i * L0_;
    const float w0 = wo[i * 3 + 0], w1 = wo[i * 3 + 1], w2 = wo[i * 3 + 2];
    float s = w1 * xr[x0 + 1] + w2 * xr[x0 + 2];
    if (x0 >= 0) s += w0 * xr[x0];
    acc += s;
  }
  out[p] = acc;
}

// Strided conv k=2 s=2 p=0: (B,64,320) -> (B,64,160)
__global__ void k_conv_d2(const float* __restrict__ x, const float* __restrict__ W,
                          const float* __restrict__ bias, float* __restrict__ out) {
  const int p = blockIdx.x * 256 + threadIdx.x;
  const int t = p % L2_;
  const int o = (p / L2_) % H_;
  const int b = p / (L2_ * H_);
  float acc = bias[o];
  const float* xb = x + (size_t)b * H_ * L1_;
  const float* wo = W + (size_t)o * H_ * 2;
  for (int i = 0; i < H_; ++i) {
    const float* xr = xb + (size_t)i * L1_;
    acc += wo[i * 2 + 0] * xr[2 * t] + wo[i * 2 + 1] * xr[2 * t + 1];
  }
  out[p] = acc;
}

// ---------------------------------------------------------------------------
// ConvTranspose1d k=3 s=2 p=1 op=1, W layout (in,out,k). out = convT(in)+bias?+skip
// ---------------------------------------------------------------------------
__global__ void k_convT(const float* in_, const float* __restrict__ W,
                        const float* __restrict__ bias, const float* __restrict__ skip,
                        float* __restrict__ out, int Lin, int Lout, int hasBias) {
  const int p = blockIdx.x * 256 + threadIdx.x;
  const int t = p % Lout;
  const int o = (p / Lout) % H_;
  const int b = p / (Lout * H_);
  float acc = hasBias ? bias[o] : 0.f;
  const float* xb = in_ + (size_t)b * H_ * Lin;
  if ((t & 1) == 0) {
    const int j = t >> 1;
    for (int i = 0; i < H_; ++i)
      acc += W[((size_t)i * H_ + o) * 3 + 1] * xb[(size_t)i * Lin + j];
  } else {
    const int j0 = (t - 1) >> 1;
    const int j1 = (t + 1) >> 1;
    const bool ok1 = j1 < Lin;
    for (int i = 0; i < H_; ++i) {
      const float* xr = xb + (size_t)i * Lin;
      acc += W[((size_t)i * H_ + o) * 3 + 2] * xr[j0];
      if (ok1) acc += W[((size_t)i * H_ + o) * 3 + 0] * xr[j1];
    }
  }
  out[p] = acc + skip[p];
}

// elementwise a += b
__global__ void k_add(float* a, const float* __restrict__ b) {
  const int p = blockIdx.x * 256 + threadIdx.x;
  a[p] += b[p];
}

// ---------------------------------------------------------------------------
// 1x1 encoder: out[b,o,l] = bias[o] + sum_i W[o,i]*in[b,i,l]  (in may == out)
// grid = B*L/256, 256 threads, one (b,l) per thread
// ---------------------------------------------------------------------------
__global__ void k_encoder(const float* __restrict__ W, const float* __restrict__ bvec,
                          const float* in_, float* out, int Lcur) {
  __shared__ float Ws[H_ * H_];
  __shared__ float bsh[H_];
  const int tid = threadIdx.x;
  for (int idx = tid; idx < H_ * H_; idx += 256) Ws[idx] = W[idx];
  if (tid < H_) bsh[tid] = bvec[tid];
  __syncthreads();
  const int p = blockIdx.x * 256 + tid;
  const int b = p / Lcur;
  const int l = p % Lcur;
  const size_t base = (size_t)b * H_ * Lcur + l;
  float xr[H_];
#pragma unroll
  for (int i = 0; i < H_; ++i) xr[i] = in_[base + (size_t)i * Lcur];
  for (int o = 0; o < H_; ++o) {
    float a = bsh[o];
    const float4* wr = (const float4*)(Ws + o * H_);
#pragma unroll
    for (int q = 0; q < 16; ++q) {
      const float4 v = wr[q];
      a += v.x * xr[4 * q] + v.y * xr[4 * q + 1] + v.z * xr[4 * q + 2] + v.w * xr[4 * q + 3];
    }
    out[base + (size_t)o * Lcur] = a;
  }
}

// ---------------------------------------------------------------------------
// Causal conv + D-skip + gelu:  y = gelu(conv(u,K) + u*D)
// One wave (64 thr) per (b,h) row. Lane owns R consecutive outputs; sliding
// register window over zero-padded K. grid = B*H.
// ---------------------------------------------------------------------------
template <int L, int R>
__global__ void k_conv_gelu(const float* __restrict__ u, const float* __restrict__ Kb,
                            const float* __restrict__ D, float* __restrict__ y) {
  const int bid = blockIdx.x;
  const int b = bid >> 6;
  const int h = bid & 63;
  const int lane = threadIdx.x;
  __shared__ float su[L];
  __shared__ float skp[2 * L];  // [0,L): zeros, [L,2L): K row
  const float* urow = u + (size_t)(b * H_ + h) * L;
  const float* krow = Kb + (size_t)h * L;
  for (int idx = lane; idx < L; idx += 64) {
    su[idx] = urow[idx];
    skp[idx] = 0.f;
    skp[L + idx] = krow[idx];
  }
  __syncthreads();
  constexpr int NLANES = L / R;
  const bool active = lane < NLANES;
  const int l0 = lane * R;
  float acc[R], w[R];
  if (active) {
#pragma unroll
    for (int r = 0; r < R; ++r) {
      acc[r] = 0.f;
      w[r] = skp[L + l0 + r];
    }
    for (int j0 = 0; j0 < L; j0 += R) {
#pragma unroll
      for (int s = 0; s < R; ++s) {
        const float uj = su[j0 + s];
#pragma unroll
        for (int r = 0; r < R; ++r) acc[r] += uj * w[(r - s + R) % R];
        w[R - 1 - s] = skp[L + l0 - j0 - s - 1];
      }
    }
  }
  __syncthreads();
  const float Dh = D[h];
  if (active) {
#pragma unroll
    for (int r = 0; r < R; ++r) {
      const float val = acc[r] + su[l0 + r] * Dh;
      const float t = 0.7978845608028654f * (val + 0.044715f * val * val * val);
      skp[l0 + r] = 0.5f * val * (1.f + tanhf(t));
    }
  }
  __syncthreads();
  float* yrow = y + (size_t)(b * H_ + h) * L;
  for (int idx = lane; idx < L; idx += 64) yrow[idx] = skp[idx];
}

// ---------------------------------------------------------------------------
// Out-proj (64->128) + GLU + residual + LayerNorm(channel).
// One (b,l) per thread; z+x staged through ybuf (global) to avoid dynamic
// register indexing. obuf may alias xbuf (in-place) or be d_out.
// ---------------------------------------------------------------------------
__global__ void k_out_glu_ln(const float* __restrict__ oW, const float* __restrict__ ob,
                             const float* __restrict__ lng, const float* __restrict__ lnb,
                             float* __restrict__ ybuf, float* xbuf, float* obuf, int Lcur) {
  __shared__ float Ws[2 * H_ * H_];  // 128x64
  __shared__ float obs[2 * H_];
  __shared__ float gs[H_], bs[H_];
  const int tid = threadIdx.x;
  for (int idx = tid; idx < 2 * H_ * H_; idx += 256) Ws[idx] = oW[idx];
  if (tid < 2 * H_) obs[tid] = ob[tid];
  if (tid < H_) { gs[tid] = lng[tid]; bs[tid] = lnb[tid]; }
  __syncthreads();
  const int p = blockIdx.x * 256 + tid;
  const int b = p / Lcur;
  const int l = p % Lcur;
  const size_t base = (size_t)b * H_ * Lcur + l;
  float yr[H_];
#pragma unroll
  for (int c = 0; c < H_; ++c) yr[c] = ybuf[base + (size_t)c * Lcur];
  float sum = 0.f, ss = 0.f;
  for (int c = 0; c < H_; ++c) {
    float a = obs[c], g = obs[c + H_];
    const float4* wa = (const float4*)(Ws + c * H_);
    const float4* wg = (const float4*)(Ws + (c + H_) * H_);
#pragma unroll
    for (int q = 0; q < 16; ++q) {
      const float4 va = wa[q], vg = wg[q];
      a += va.x * yr[4 * q] + va.y * yr[4 * q + 1] + va.z * yr[4 * q + 2] + va.w * yr[4 * q + 3];
      g += vg.x * yr[4 * q] + vg.y * yr[4 * q + 1] + vg.z * yr[4 * q + 2] + vg.w * yr[4 * q + 3];
    }
    const float z = a / (1.f + expf(-g));           // a * sigmoid(g)
    const float wv = z + xbuf[base + (size_t)c * Lcur];
    sum += wv;
    ss += wv * wv;
    ybuf[base + (size_t)c * Lcur] = wv;             // stage z+x (yr already in regs)
  }
  const float mean = sum * (1.f / 64.f);
  const float var = ss * (1.f / 64.f) - mean * mean;
  const float rstd = rsqrtf(var + 1e-5f);
  for (int c = 0; c < H_; ++c) {
    const float wv = ybuf[base + (size_t)c * Lcur];
    obuf[base + (size_t)c * Lcur] = (wv - mean) * rstd * gs[c] + bs[c];
  }
}

}  // namespace

// ---------------------------------------------------------------------------
extern "C" void kernel_launch(void* const* d_in, const int* in_sizes, int n_in,
                              void* d_out, int out_size, void* d_ws, size_t ws_size,
                              hipStream_t stream) {
  const float* x       = (const float*)d_in[0];
  const float* enc_W   = (const float*)d_in[1];
  const float* enc_b   = (const float*)d_in[2];
  const float* ln_g    = (const float*)d_in[3];
  const float* ln_b    = (const float*)d_in[4];
  const float* s4_D    = (const float*)d_in[5];
  const float* s4_ldt  = (const float*)d_in[6];
  const float* s4_C    = (const float*)d_in[7];
  const float* s4_logA = (const float*)d_in[8];
  const float* s4_Aim  = (const float*)d_in[9];
  const float* out_W   = (const float*)d_in[10];
  const float* out_b   = (const float*)d_in[11];
  const float* cd1_W   = (const float*)d_in[12];
  const float* cd1_b   = (const float*)d_in[13];
  const float* cd2_W   = (const float*)d_in[14];
  const float* cd2_b   = (const float*)d_in[15];
  const float* up_W    = (const float*)d_in[16];
  const float* up_b    = (const float*)d_in[17];
  const float* up1_W   = (const float*)d_in[18];
  float* outp = (float*)d_out;

  // Workspace layout (floats); total ~112.2 MB
  float* ws   = (float*)d_ws;
  float* bufA = ws;                                   // B*H*L0
  float* bufB = bufA + (size_t)B_ * H_ * L0_;         // B*H*L0
  float* enc1 = bufB + (size_t)B_ * H_ * L0_;         // B*H*L1
  float* enc2 = enc1 + (size_t)B_ * H_ * L1_;         // B*H*L2
  float* Kb   = enc2 + (size_t)B_ * H_ * L2_;         // NL*H*(L2+L1+L0)

  const size_t koff0 = 0;
  const size_t koff1 = (size_t)NL_ * H_ * L2_;
  const size_t koff2 = koff1 + (size_t)NL_ * H_ * L1_;

  // All 24 layers' conv kernels K (data-independent)
  k_compute_K<<<NM_ * NL_ * H_, 256, 0, stream>>>(s4_ldt, s4_C, s4_logA, s4_Aim, Kb);

  // enc1 = conv_d1(x), enc2 = conv_d2(enc1)
  k_conv_d1<<<(B_ * H_ * L1_) / 256, 256, 0, stream>>>(x, cd1_W, cd1_b, enc1);
  k_conv_d2<<<(B_ * H_ * L2_) / 256, 256, 0, stream>>>(enc1, cd2_W, cd2_b, enc2);

  auto run_model = [&](int m, const float* input, float* state, float* scratch,
                       int Lm, size_t koff, float* final_out) {
    const int BL = B_ * Lm;
    k_encoder<<<BL / 256, 256, 0, stream>>>(enc_W + (size_t)m * H_ * H_,
                                            enc_b + (size_t)m * H_, input, state, Lm);
    for (int i = 0; i < NL_; ++i) {
      const float* Kl = Kb + koff + (size_t)i * H_ * Lm;
      const float* Dl = s4_D + ((size_t)m * NL_ + i) * H_;
      if (Lm == L2_)
        k_conv_gelu<L2_, 5><<<B_ * H_, 64, 0, stream>>>(state, Kl, Dl, scratch);
      else if (Lm == L1_)
        k_conv_gelu<L1_, 5><<<B_ * H_, 64, 0, stream>>>(state, Kl, Dl, scratch);
      else
        k_conv_gelu<L0_, 10><<<B_ * H_, 64, 0, stream>>>(state, Kl, Dl, scratch);
      float* obuf = (i == NL_ - 1 && final_out) ? final_out : state;
      k_out_glu_ln<<<BL / 256, 256, 0, stream>>>(
          out_W + ((size_t)m * NL_ + i) * 2 * H_ * H_,
          out_b + ((size_t)m * NL_ + i) * 2 * H_,
          ln_g + ((size_t)m * NL_ + i) * H_,
          ln_b + ((size_t)m * NL_ + i) * H_,
          scratch, state, obuf, Lm);
    }
  };

  // model 0 on enc2 (L=160)
  run_model(0, enc2, bufA, bufB, L2_, koff0, nullptr);
  // dec1 = enc2 + enc21   (in place into enc2)
  k_add<<<(B_ * H_ * L2_) / 256, 256, 0, stream>>>(enc2, bufA);
  // dec21 = convT(dec1, up_W) + up_b + enc1  -> bufA
  k_convT<<<(B_ * H_ * L1_) / 256, 256, 0, stream>>>(enc2, up_W, up_b, enc1, bufA, L2_, L1_, 1);
  // model 1 on dec21 (L=320), in place in bufA
  run_model(1, bufA, bufA, bufB, L1_, koff1, nullptr);
  // dec32 = convT(dec2, up1_W) + enc0  -> bufB
  k_convT<<<(B_ * H_ * L0_) / 256, 256, 0, stream>>>(bufA, up1_W, nullptr, x, bufB, L1_, L0_, 0);
  // model 2 on dec32 (L=640); final layer writes d_out
  run_model(2, bufB, bufB, bufA, L0_, koff2, outp);
}